// Round 4
// baseline (550.433 us; speedup 1.0000x reference)
//
#include <hip/hip_runtime.h>

// EM routing (matrix capsules), B=16,H=6,W=6,KH=KW=3,I=32,O=32,A=4, ITERATIONS=2.
//
// R6 = R5 + K3 i-pairing (latency attack).
//  K1: (site, p-quarter) float4 streaming moments -> mu1/i2s/base/m1 tables. (unchanged)
//  K3: (site, 4-i group), 256 thr, now TWO phases of an i-PAIR each:
//      - both i's votes loaded up front (12 independent dwordx4 -> 1 HBM
//        round-trip per phase; was 1 serialized trip per i),
//      - two independent LSE shuffle chains interleaved (ILP hides the
//        12-step ds_bpermute latency),
//      - 2 barriers per block (was 4),
//      - kk=8 tail split across full wave 0: lane o and lane 32+o each
//        handle 8 of the 16 a's, folded via shfl_xor(32); tail stays in
//        registers (no reload). exp(ln2)/accw single-counted by t<32 guard.
//  K4: sum 8 partials/site, 0.2*M1 mix, finalize mu2/sig2/a_j2. (unchanged)
// Fixed harness overhead (ws poison ~205us + in restore ~108us) untouchable;
// kernel budget ~200us vs ~120us floor; K3 (~135us) is latency-bound.

#define KKc 9
#define NIc 32
#define NOc 32
#define NAc 16
#define KIc 288    // KKc*NIc
#define NPc 512    // NOc*NAc
#define NSITE 576

#define EPSf 1e-7f
#define TWO_PIf 6.28318530717958647692f

__device__ __forceinline__ float wave_sum(float v) {     // valid in lane 0 only
#pragma unroll
  for (int off = 32; off; off >>= 1) v += __shfl_down(v, off, 64);
  return v;
}
__device__ __forceinline__ float wave_max_all(float v) { // butterfly: valid in ALL lanes
#pragma unroll
  for (int off = 32; off; off >>= 1) v = fmaxf(v, __shfl_xor(v, off, 64));
  return v;
}

// ---------------- K1: M-step-1 ----------------
// grid 2304 = site*4+qtr; block 128. Thread owns float4 col c = qtr*32+(t&31),
// rows ki = (t>>5) + 4k. Cross-row fold: shfl_xor(32) then 1 LDS hop.
__global__ __launch_bounds__(128)
void em_k1(const float* __restrict__ votes, const float* __restrict__ acts_in,
           const float* __restrict__ beta_a, const float* __restrict__ beta_u,
           float* __restrict__ w_mu1, float* __restrict__ w_i2s,
           float* __restrict__ w_m1v, float* __restrict__ w_m1q,
           float* __restrict__ w_base, float* __restrict__ w_sR1)
{
  const int site = blockIdx.x >> 2;
  const int qtr  = blockIdx.x & 3;
  const int t    = threadIdx.x;

  __shared__ float s_act[KIc];
  __shared__ float s_red[2];
  __shared__ float s_cr[32 * 9];

  s_act[t] = acts_in[site * KIc + t];
  s_act[t + 128] = acts_in[site * KIc + t + 128];
  if (t < 32) s_act[t + 256] = acts_in[site * KIc + t + 256];
  __syncthreads();

  float v = fmaf(0.8f, s_act[t], 0.2f) + fmaf(0.8f, s_act[t + 128], 0.2f);
  if (t < 32) v += fmaf(0.8f, s_act[t + 256], 0.2f);
  v = wave_sum(v);
  if ((t & 63) == 0) s_red[t >> 6] = v;
  __syncthreads();
  const float sumR1 = (s_red[0] + s_red[1]) * 0.03125f;

  const int c  = qtr * 32 + (t & 31);   // float4 column 0..127
  const int r0 = t >> 5;                // 0..3
  float pv0 = 0.f, pv1 = 0.f, pv2 = 0.f, pv3 = 0.f;
  float pq0 = 0.f, pq1 = 0.f, pq2 = 0.f, pq3 = 0.f;
  const float4* vb = reinterpret_cast<const float4*>(votes) + (size_t)site * (KIc * 128) + c;
#pragma unroll 8
  for (int k = 0; k < 72; ++k) {
    const int ki = r0 + 4 * k;
    const float r = fmaf(0.8f, s_act[ki], 0.2f) * 0.03125f;
    const float4 x = vb[(size_t)ki * 128];
    pv0 = fmaf(r, x.x, pv0); pq0 = fmaf(r, x.x * x.x, pq0);
    pv1 = fmaf(r, x.y, pv1); pq1 = fmaf(r, x.y * x.y, pq1);
    pv2 = fmaf(r, x.z, pv2); pq2 = fmaf(r, x.z * x.z, pq2);
    pv3 = fmaf(r, x.w, pv3); pq3 = fmaf(r, x.w * x.w, pq3);
  }
  // fold rows r0 pairs within wave
  pv0 += __shfl_xor(pv0, 32); pv1 += __shfl_xor(pv1, 32);
  pv2 += __shfl_xor(pv2, 32); pv3 += __shfl_xor(pv3, 32);
  pq0 += __shfl_xor(pq0, 32); pq1 += __shfl_xor(pq1, 32);
  pq2 += __shfl_xor(pq2, 32); pq3 += __shfl_xor(pq3, 32);
  if (t >= 64 && t < 96) {
    const int l = t - 64;
    s_cr[l * 9 + 0] = pv0; s_cr[l * 9 + 1] = pv1; s_cr[l * 9 + 2] = pv2; s_cr[l * 9 + 3] = pv3;
    s_cr[l * 9 + 4] = pq0; s_cr[l * 9 + 5] = pq1; s_cr[l * 9 + 6] = pq2; s_cr[l * 9 + 7] = pq3;
  }
  __syncthreads();
  if (t < 32) {
    pv0 += s_cr[t * 9 + 0]; pv1 += s_cr[t * 9 + 1]; pv2 += s_cr[t * 9 + 2]; pv3 += s_cr[t * 9 + 3];
    pq0 += s_cr[t * 9 + 4]; pq1 += s_cr[t * 9 + 5]; pq2 += s_cr[t * 9 + 6]; pq3 += s_cr[t * 9 + 7];

    const float sR1e = sumR1 + EPSf;
    const float sR1x = sumR1 + 2.f * EPSf;
    const float mu0 = pv0 / sR1e, mu1 = pv1 / sR1e, mu2 = pv2 / sR1e, mu3 = pv3 / sR1e;
    const float sg0 = fmaxf((pq0 - mu0 * mu0 * sR1x) / sR1e, 0.f);
    const float sg1 = fmaxf((pq1 - mu1 * mu1 * sR1x) / sR1e, 0.f);
    const float sg2 = fmaxf((pq2 - mu2 * mu2 * sR1x) / sR1e, 0.f);
    const float sg3 = fmaxf((pq3 - mu3 * mu3 * sR1x) / sR1e, 0.f);

    const size_t fo = (size_t)site * 128 + c;
    reinterpret_cast<float4*>(w_mu1)[fo] = make_float4(mu0, mu1, mu2, mu3);
    reinterpret_cast<float4*>(w_i2s)[fo] = make_float4(0.5f / sg0, 0.5f / sg1, 0.5f / sg2, 0.5f / sg3);
    reinterpret_cast<float4*>(w_m1v)[fo] = make_float4(pv0, pv1, pv2, pv3);
    reinterpret_cast<float4*>(w_m1q)[fo] = make_float4(pq0, pq1, pq2, pq3);

    const int o = c >> 2;
    const float bu = beta_u[o];
    float lt = logf(TWO_PIf * sg0 + EPSf) + logf(TWO_PIf * sg1 + EPSf)
             + logf(TWO_PIf * sg2 + EPSf) + logf(TWO_PIf * sg3 + EPSf);
    float ch = (4.f * bu - 0.5f * (logf(sg0 + EPSf) + logf(sg1 + EPSf)
                                 + logf(sg2 + EPSf) + logf(sg3 + EPSf))) * sumR1;
    ch += __shfl_xor(ch, 1); ch += __shfl_xor(ch, 2);
    lt += __shfl_xor(lt, 1); lt += __shfl_xor(lt, 2);
    if ((t & 3) == 0) {
      // inv_temp (it=0) = 0.01*(1-0.95) = 0.0005
      const float aj = 1.f / (1.f + expf(-(0.0005f * (beta_a[o] - ch))));
      w_base[site * NOc + o] = logf(aj + EPSf) - lt;
    }
    if (t == 0) w_sR1[site] = sumR1;
  }
}

// ---------------- K3: E-step + M-step-2 partials (register-direct, i-paired) ----
// grid 4608; block 256. site reversed for L2/L3 reuse of K1's tail.
// Thread (kk = t>>5, o = t&31) owns votes[site,kk,i,o,0:16] (contiguous 64B).
// Wave 0 additionally owns the kk=8 tail rows: lane o handles a=0..7, lane
// 32+o handles a=8..15 of row (kk=8, o); halves folded via shfl_xor(32).
__global__ __launch_bounds__(256)
void em_k3(const float* __restrict__ votes, const float* __restrict__ acts_in,
           const float* __restrict__ w_mu1, const float* __restrict__ w_i2s,
           const float* __restrict__ w_base, float* __restrict__ w_part)
{
  const int site = (NSITE - 1) - (blockIdx.x >> 3);
  const int ig   = blockIdx.x & 7;
  const int t    = threadIdx.x;
  const int o    = t & 31;
  const int kk   = t >> 5;          // 0..7

  __shared__ float s_act[KIc];
  __shared__ float s_lse[2][16];    // [phase][wave*4 + {mA,eA,mB,eB}]
  __shared__ float s_p[33 * 128];   // 16896B block-reduction buffer

  s_act[t] = acts_in[site * KIc + t];
  if (t < 32) s_act[256 + t] = acts_in[site * KIc + 256 + t];
  // (visibility of s_act is covered by the first in-loop barrier)

  // per-thread mu/i2s tables for capsule o, straight from global (L2/L3-hot)
  float mu[16], is[16];
  {
    const float4* mp = reinterpret_cast<const float4*>(w_mu1 + (size_t)site * NPc) + o * 4;
    const float4* ip = reinterpret_cast<const float4*>(w_i2s + (size_t)site * NPc) + o * 4;
#pragma unroll
    for (int j = 0; j < 4; ++j) {
      const float4 a = mp[j];
      mu[4 * j] = a.x; mu[4 * j + 1] = a.y; mu[4 * j + 2] = a.z; mu[4 * j + 3] = a.w;
      const float4 b = ip[j];
      is[4 * j] = b.x; is[4 * j + 1] = b.y; is[4 * j + 2] = b.z; is[4 * j + 3] = b.w;
    }
  }
  const float lbase = w_base[site * NOc + o];

  float accv[16], accq[16], accw = 0.f;
#pragma unroll
  for (int a = 0; a < 16; ++a) { accv[a] = 0.f; accq[a] = 0.f; }

  const float4* vbase = reinterpret_cast<const float4*>(votes) + (size_t)site * (KIc * 128);
  const float4* vrow  = vbase + o * 4;
  const int h = (t >> 5) & 1;       // tail half (meaningful for t<64)
  const float4* vt0 = vbase + (size_t)256 * 128 + o * 4 + 2 * h;   // + i*128 per i

  for (int p = 0; p < 2; ++p) {
    const int ia = ig * 4 + 2 * p;
    const int ib = ia + 1;

    // ---- issue ALL of this phase's loads up front (independent dwordx4) ----
    float va[16], vb[16];
    {
      const float4* pa = vrow + (size_t)(kk * NIc + ia) * 128;
#pragma unroll
      for (int j = 0; j < 4; ++j) {
        const float4 x = pa[j];
        va[4 * j] = x.x; va[4 * j + 1] = x.y; va[4 * j + 2] = x.z; va[4 * j + 3] = x.w;
      }
#pragma unroll
      for (int j = 0; j < 4; ++j) {
        const float4 x = pa[128 + j];           // row ib = ia+1
        vb[4 * j] = x.x; vb[4 * j + 1] = x.y; vb[4 * j + 2] = x.z; vb[4 * j + 3] = x.w;
      }
    }
    float4 Ta0, Ta1, Tb0, Tb1;
    if (t < 64) {
      const float4* pt = vt0 + (size_t)ia * 128;
      Ta0 = pt[0]; Ta1 = pt[1];                 // tail row of ia, this half's 8 a's
      Tb0 = pt[128]; Tb1 = pt[129];             // tail row of ib
    }

    // ---- log-numerators ----
    float lpa = 0.f, lpb = 0.f;
#pragma unroll
    for (int a = 0; a < 16; ++a) {
      const float da = va[a] - mu[a]; lpa = fmaf(da * da, is[a], lpa);
      const float db = vb[a] - mu[a]; lpb = fmaf(db * db, is[a], lpb);
    }
    const float ln1a = lbase - lpa;
    const float ln1b = lbase - lpb;

    float ln2a = -1e30f, ln2b = -1e30f;
    if (t < 64) {
      const int a0 = 8 * h;
      float tpa = 0.f, tpb = 0.f;
      float d;
      d = Ta0.x - mu[a0 + 0]; tpa = fmaf(d * d, is[a0 + 0], tpa);
      d = Ta0.y - mu[a0 + 1]; tpa = fmaf(d * d, is[a0 + 1], tpa);
      d = Ta0.z - mu[a0 + 2]; tpa = fmaf(d * d, is[a0 + 2], tpa);
      d = Ta0.w - mu[a0 + 3]; tpa = fmaf(d * d, is[a0 + 3], tpa);
      d = Ta1.x - mu[a0 + 4]; tpa = fmaf(d * d, is[a0 + 4], tpa);
      d = Ta1.y - mu[a0 + 5]; tpa = fmaf(d * d, is[a0 + 5], tpa);
      d = Ta1.z - mu[a0 + 6]; tpa = fmaf(d * d, is[a0 + 6], tpa);
      d = Ta1.w - mu[a0 + 7]; tpa = fmaf(d * d, is[a0 + 7], tpa);
      d = Tb0.x - mu[a0 + 0]; tpb = fmaf(d * d, is[a0 + 0], tpb);
      d = Tb0.y - mu[a0 + 1]; tpb = fmaf(d * d, is[a0 + 1], tpb);
      d = Tb0.z - mu[a0 + 2]; tpb = fmaf(d * d, is[a0 + 2], tpb);
      d = Tb0.w - mu[a0 + 3]; tpb = fmaf(d * d, is[a0 + 3], tpb);
      d = Tb1.x - mu[a0 + 4]; tpb = fmaf(d * d, is[a0 + 4], tpb);
      d = Tb1.y - mu[a0 + 5]; tpb = fmaf(d * d, is[a0 + 5], tpb);
      d = Tb1.z - mu[a0 + 6]; tpb = fmaf(d * d, is[a0 + 6], tpb);
      d = Tb1.w - mu[a0 + 7]; tpb = fmaf(d * d, is[a0 + 7], tpb);
      tpa += __shfl_xor(tpa, 32);               // fold the two 8-a halves
      tpb += __shfl_xor(tpb, 32);
      ln2a = lbase - tpa;
      ln2b = lbase - tpb;
    }

    // ---- two independent per-wave LSE partials (chains interleave) ----
    const float mwa = wave_max_all(fmaxf(ln1a, ln2a));
    const float mwb = wave_max_all(fmaxf(ln1b, ln2b));
    float ea = expf(ln1a - mwa) + ((t < 32) ? expf(ln2a - mwa) : 0.f); // tail counted once
    float eb = expf(ln1b - mwb) + ((t < 32) ? expf(ln2b - mwb) : 0.f);
    ea = wave_sum(ea);
    eb = wave_sum(eb);
    if ((t & 63) == 0) {
      const int w4 = (t >> 6) * 4;
      s_lse[p][w4 + 0] = mwa; s_lse[p][w4 + 1] = ea;
      s_lse[p][w4 + 2] = mwb; s_lse[p][w4 + 3] = eb;
    }
    __syncthreads();                            // the ONLY barrier this phase
    const float gma = fmaxf(fmaxf(s_lse[p][0], s_lse[p][4]),
                            fmaxf(s_lse[p][8], s_lse[p][12]));
    const float dena = s_lse[p][1] * expf(s_lse[p][0] - gma)
                     + s_lse[p][5] * expf(s_lse[p][4] - gma)
                     + s_lse[p][9] * expf(s_lse[p][8] - gma)
                     + s_lse[p][13] * expf(s_lse[p][12] - gma);
    const float logdena = gma + logf(dena);
    const float gmb = fmaxf(fmaxf(s_lse[p][2], s_lse[p][6]),
                            fmaxf(s_lse[p][10], s_lse[p][14]));
    const float denb = s_lse[p][3] * expf(s_lse[p][2] - gmb)
                     + s_lse[p][7] * expf(s_lse[p][6] - gmb)
                     + s_lse[p][11] * expf(s_lse[p][10] - gmb)
                     + s_lse[p][15] * expf(s_lse[p][14] - gmb);
    const float logdenb = gmb + logf(denb);

    // ---- weights + moment accumulation, all registers ----
    const float w1a = expf(ln1a - logdena) * s_act[kk * NIc + ia] * 0.8f;
    const float w1b = expf(ln1b - logdenb) * s_act[kk * NIc + ib] * 0.8f;
    accw += w1a + w1b;
#pragma unroll
    for (int a = 0; a < 16; ++a) {
      accv[a] = fmaf(w1b, vb[a], fmaf(w1a, va[a], accv[a]));
      accq[a] = fmaf(w1b, vb[a] * vb[a], fmaf(w1a, va[a] * va[a], accq[a]));
    }
    if (t < 64) {
      const float w2a = expf(ln2a - logdena) * s_act[8 * NIc + ia] * 0.8f;
      const float w2b = expf(ln2b - logdenb) * s_act[8 * NIc + ib] * 0.8f;
      if (t < 32) accw += w2a + w2b;            // per-row weight counted once
      const int a0 = 8 * h;                     // this half's 8 a's
      accv[a0 + 0] = fmaf(w2b, Tb0.x, fmaf(w2a, Ta0.x, accv[a0 + 0]));
      accq[a0 + 0] = fmaf(w2b, Tb0.x * Tb0.x, fmaf(w2a, Ta0.x * Ta0.x, accq[a0 + 0]));
      accv[a0 + 1] = fmaf(w2b, Tb0.y, fmaf(w2a, Ta0.y, accv[a0 + 1]));
      accq[a0 + 1] = fmaf(w2b, Tb0.y * Tb0.y, fmaf(w2a, Ta0.y * Ta0.y, accq[a0 + 1]));
      accv[a0 + 2] = fmaf(w2b, Tb0.z, fmaf(w2a, Ta0.z, accv[a0 + 2]));
      accq[a0 + 2] = fmaf(w2b, Tb0.z * Tb0.z, fmaf(w2a, Ta0.z * Ta0.z, accq[a0 + 2]));
      accv[a0 + 3] = fmaf(w2b, Tb0.w, fmaf(w2a, Ta0.w, accv[a0 + 3]));
      accq[a0 + 3] = fmaf(w2b, Tb0.w * Tb0.w, fmaf(w2a, Ta0.w * Ta0.w, accq[a0 + 3]));
      accv[a0 + 4] = fmaf(w2b, Tb1.x, fmaf(w2a, Ta1.x, accv[a0 + 4]));
      accq[a0 + 4] = fmaf(w2b, Tb1.x * Tb1.x, fmaf(w2a, Ta1.x * Ta1.x, accq[a0 + 4]));
      accv[a0 + 5] = fmaf(w2b, Tb1.y, fmaf(w2a, Ta1.y, accv[a0 + 5]));
      accq[a0 + 5] = fmaf(w2b, Tb1.y * Tb1.y, fmaf(w2a, Ta1.y * Ta1.y, accq[a0 + 5]));
      accv[a0 + 6] = fmaf(w2b, Tb1.z, fmaf(w2a, Ta1.z, accv[a0 + 6]));
      accq[a0 + 6] = fmaf(w2b, Tb1.z * Tb1.z, fmaf(w2a, Ta1.z * Ta1.z, accq[a0 + 6]));
      accv[a0 + 7] = fmaf(w2b, Tb1.w, fmaf(w2a, Ta1.w, accv[a0 + 7]));
      accq[a0 + 7] = fmaf(w2b, Tb1.w * Tb1.w, fmaf(w2a, Ta1.w * Ta1.w, accq[a0 + 7]));
    }
  }

  // ---- block reduction over kk: shfl fold + 4-wave LDS combine ----
  accw += __shfl_xor(accw, 32);
#pragma unroll
  for (int a = 0; a < 16; ++a) {
    accv[a] += __shfl_xor(accv[a], 32);
    accq[a] += __shfl_xor(accq[a], 32);
  }
  {
    const int l = t & 63, wv = t >> 6;
    if (l < 32) {
#pragma unroll
      for (int a = 0; a < 16; ++a) {
        s_p[a * 128 + wv * 32 + l] = accv[a];
        s_p[(16 + a) * 128 + wv * 32 + l] = accq[a];
      }
      s_p[32 * 128 + wv * 32 + l] = accw;
    }
  }
  __syncthreads();
  float* wp = w_part + (size_t)(site * 8 + ig) * (33 * 32);
  for (int j = t >> 5; j < 33; j += 8) {
    const float s = s_p[j * 128 + o] + s_p[j * 128 + 32 + o]
                  + s_p[j * 128 + 64 + o] + s_p[j * 128 + 96 + o];
    wp[j * 32 + o] = s;
  }
}

// ---------------- K4: finalize ----------------
__global__ __launch_bounds__(256)
void em_k4(const float* __restrict__ beta_a, const float* __restrict__ beta_u,
           const float* __restrict__ w_m1v, const float* __restrict__ w_m1q,
           const float* __restrict__ w_sR1, const float* __restrict__ w_part,
           float* __restrict__ out)
{
  const int site = blockIdx.x;
  const int t    = threadIdx.x;
  const int oB   = t & 31;
  const int a2B  = (t >> 5) * 2;

  __shared__ float s_M[33 * 32];
  __shared__ float s_c[256];

  for (int j = t >> 5; j < 33; j += 8) {
    float s = 0.f;
#pragma unroll
    for (int g = 0; g < 8; ++g)
      s += w_part[(size_t)(site * 8 + g) * (33 * 32) + j * 32 + oB];
    s_M[j * 32 + oB] = s;
  }
  __syncthreads();

  const float sumR1 = w_sR1[site];
  const float sumR  = s_M[32 * 32 + oB] + 0.2f * sumR1;
  const float sRe   = sumR + EPSf;
  const float sRx   = sumR + 2.f * EPSf;
  const int p = oB * NAc + a2B;

  const float Mva = s_M[a2B * 32 + oB]        + 0.2f * w_m1v[(size_t)site * NPc + p];
  const float Mvb = s_M[(a2B + 1) * 32 + oB]  + 0.2f * w_m1v[(size_t)site * NPc + p + 1];
  const float Mqa = s_M[(16 + a2B) * 32 + oB] + 0.2f * w_m1q[(size_t)site * NPc + p];
  const float Mqb = s_M[(17 + a2B) * 32 + oB] + 0.2f * w_m1q[(size_t)site * NPc + p + 1];

  const float mua = Mva / sRe;
  const float mub = Mvb / sRe;
  const float sga = fmaxf((Mqa - mua * mua * sRx) / sRe, 0.f);
  const float sgb = fmaxf((Mqb - mub * mub * sRx) / sRe, 0.f);

  reinterpret_cast<float2*>(out + (size_t)site * NPc)[p >> 1] = make_float2(mua, mub);

  const float bu = beta_u[oB];
  s_c[t] = (bu - 0.5f * logf(sga + EPSf)) * sumR
         + (bu - 0.5f * logf(sgb + EPSf)) * sumR;
  __syncthreads();
  if (t < NOc) {
    float c = 0.f;
#pragma unroll
    for (int k = 0; k < 8; ++k) c += s_c[t + 32 * k];
    // inv_temp (it_idx=ITERATIONS=2) = 0.01*(1-0.95^3) = 0.00142625
    const float aj = 1.f / (1.f + expf(-(0.00142625f * (beta_a[t] - c))));
    out[(size_t)NSITE * NPc + site * NOc + t] = aj;
  }
}

extern "C" void kernel_launch(void* const* d_in, const int* in_sizes, int n_in,
                              void* d_out, int out_size, void* d_ws, size_t ws_size,
                              hipStream_t stream) {
  const float* votes  = (const float*)d_in[0];
  const float* acts   = (const float*)d_in[1];
  const float* beta_a = (const float*)d_in[2];
  const float* beta_u = (const float*)d_in[3];
  float* out = (float*)d_out;

  float* ws = (float*)d_ws;
  const size_t SP = (size_t)NSITE * NPc;        // 294912
  float* w_mu1  = ws;
  float* w_i2s  = ws + SP;
  float* w_m1v  = ws + 2 * SP;
  float* w_m1q  = ws + 3 * SP;
  float* w_base = ws + 4 * SP;                  // 576*32
  float* w_sR1  = w_base + NSITE * NOc;         // 576 (padded to 1024)
  float* w_part = w_sR1 + 1024;                 // 4608*33*32 floats (~19.5MB)

  em_k1<<<NSITE * 4, 128, 0, stream>>>(votes, acts, beta_a, beta_u,
                                       w_mu1, w_i2s, w_m1v, w_m1q, w_base, w_sR1);
  em_k3<<<NSITE * 8, 256, 0, stream>>>(votes, acts, w_mu1, w_i2s, w_base, w_part);
  em_k4<<<NSITE, 256, 0, stream>>>(beta_a, beta_u, w_m1v, w_m1q, w_sR1, w_part, out);
}

// Round 5
// 526.578 us; speedup vs baseline: 1.0453x; 1.0453x over previous
//
#include <hip/hip_runtime.h>

// EM routing (matrix capsules), B=16,H=6,W=6,KH=KW=3,I=32,O=32,A=4, ITERATIONS=2.
//
// R7 = R5 + K3 register-pressure attack (occupancy lever).
//  R6 post-mortem: i-pairing (+48 live VGPRs) crossed the 128-VGPR occupancy
//  cliff (4 -> 2 waves/SIMD) and REGRESSED +34us. K3 is latency-bound via
//  occupancy, so R7 pushes K3 safely UNDER the cliff instead:
//   - __launch_bounds__(256,4): min 4 waves/SIMD => VGPR <= 128 enforced.
//   - v1 is consumed into lp1 at load time and RELOADED (L1-hot, pointer
//     obfuscated vs CSE) for the moment accumulation -> its 16 regs are dead
//     across the 12-deep LSE shuffle chain. Tail reload obfuscated likewise.
//  K1: (site, p-quarter) float4 streaming moments -> mu1/i2s/base/m1. (unchanged)
//  K3: (site, 4-i group), 256 thr, register-direct, 1 barrier per i.
//  K4: sum 8 partials/site, 0.2*M1 mix, finalize mu2/sig2/a_j2. (unchanged)
// Fixed harness overhead (ws poison ~205us + in restore ~108us) untouchable.

#define KKc 9
#define NIc 32
#define NOc 32
#define NAc 16
#define KIc 288    // KKc*NIc
#define NPc 512    // NOc*NAc
#define NSITE 576

#define EPSf 1e-7f
#define TWO_PIf 6.28318530717958647692f

__device__ __forceinline__ float wave_sum(float v) {     // valid in lane 0 only
#pragma unroll
  for (int off = 32; off; off >>= 1) v += __shfl_down(v, off, 64);
  return v;
}
__device__ __forceinline__ float wave_max_all(float v) { // butterfly: valid in ALL lanes
#pragma unroll
  for (int off = 32; off; off >>= 1) v = fmaxf(v, __shfl_xor(v, off, 64));
  return v;
}

// ---------------- K1: M-step-1 ----------------
// grid 2304 = site*4+qtr; block 128. Thread owns float4 col c = qtr*32+(t&31),
// rows ki = (t>>5) + 4k. Cross-row fold: shfl_xor(32) then 1 LDS hop.
__global__ __launch_bounds__(128)
void em_k1(const float* __restrict__ votes, const float* __restrict__ acts_in,
           const float* __restrict__ beta_a, const float* __restrict__ beta_u,
           float* __restrict__ w_mu1, float* __restrict__ w_i2s,
           float* __restrict__ w_m1v, float* __restrict__ w_m1q,
           float* __restrict__ w_base, float* __restrict__ w_sR1)
{
  const int site = blockIdx.x >> 2;
  const int qtr  = blockIdx.x & 3;
  const int t    = threadIdx.x;

  __shared__ float s_act[KIc];
  __shared__ float s_red[2];
  __shared__ float s_cr[32 * 9];

  s_act[t] = acts_in[site * KIc + t];
  s_act[t + 128] = acts_in[site * KIc + t + 128];
  if (t < 32) s_act[t + 256] = acts_in[site * KIc + t + 256];
  __syncthreads();

  float v = fmaf(0.8f, s_act[t], 0.2f) + fmaf(0.8f, s_act[t + 128], 0.2f);
  if (t < 32) v += fmaf(0.8f, s_act[t + 256], 0.2f);
  v = wave_sum(v);
  if ((t & 63) == 0) s_red[t >> 6] = v;
  __syncthreads();
  const float sumR1 = (s_red[0] + s_red[1]) * 0.03125f;

  const int c  = qtr * 32 + (t & 31);   // float4 column 0..127
  const int r0 = t >> 5;                // 0..3
  float pv0 = 0.f, pv1 = 0.f, pv2 = 0.f, pv3 = 0.f;
  float pq0 = 0.f, pq1 = 0.f, pq2 = 0.f, pq3 = 0.f;
  const float4* vb = reinterpret_cast<const float4*>(votes) + (size_t)site * (KIc * 128) + c;
#pragma unroll 8
  for (int k = 0; k < 72; ++k) {
    const int ki = r0 + 4 * k;
    const float r = fmaf(0.8f, s_act[ki], 0.2f) * 0.03125f;
    const float4 x = vb[(size_t)ki * 128];
    pv0 = fmaf(r, x.x, pv0); pq0 = fmaf(r, x.x * x.x, pq0);
    pv1 = fmaf(r, x.y, pv1); pq1 = fmaf(r, x.y * x.y, pq1);
    pv2 = fmaf(r, x.z, pv2); pq2 = fmaf(r, x.z * x.z, pq2);
    pv3 = fmaf(r, x.w, pv3); pq3 = fmaf(r, x.w * x.w, pq3);
  }
  // fold rows r0 pairs within wave
  pv0 += __shfl_xor(pv0, 32); pv1 += __shfl_xor(pv1, 32);
  pv2 += __shfl_xor(pv2, 32); pv3 += __shfl_xor(pv3, 32);
  pq0 += __shfl_xor(pq0, 32); pq1 += __shfl_xor(pq1, 32);
  pq2 += __shfl_xor(pq2, 32); pq3 += __shfl_xor(pq3, 32);
  if (t >= 64 && t < 96) {
    const int l = t - 64;
    s_cr[l * 9 + 0] = pv0; s_cr[l * 9 + 1] = pv1; s_cr[l * 9 + 2] = pv2; s_cr[l * 9 + 3] = pv3;
    s_cr[l * 9 + 4] = pq0; s_cr[l * 9 + 5] = pq1; s_cr[l * 9 + 6] = pq2; s_cr[l * 9 + 7] = pq3;
  }
  __syncthreads();
  if (t < 32) {
    pv0 += s_cr[t * 9 + 0]; pv1 += s_cr[t * 9 + 1]; pv2 += s_cr[t * 9 + 2]; pv3 += s_cr[t * 9 + 3];
    pq0 += s_cr[t * 9 + 4]; pq1 += s_cr[t * 9 + 5]; pq2 += s_cr[t * 9 + 6]; pq3 += s_cr[t * 9 + 7];

    const float sR1e = sumR1 + EPSf;
    const float sR1x = sumR1 + 2.f * EPSf;
    const float mu0 = pv0 / sR1e, mu1 = pv1 / sR1e, mu2 = pv2 / sR1e, mu3 = pv3 / sR1e;
    const float sg0 = fmaxf((pq0 - mu0 * mu0 * sR1x) / sR1e, 0.f);
    const float sg1 = fmaxf((pq1 - mu1 * mu1 * sR1x) / sR1e, 0.f);
    const float sg2 = fmaxf((pq2 - mu2 * mu2 * sR1x) / sR1e, 0.f);
    const float sg3 = fmaxf((pq3 - mu3 * mu3 * sR1x) / sR1e, 0.f);

    const size_t fo = (size_t)site * 128 + c;
    reinterpret_cast<float4*>(w_mu1)[fo] = make_float4(mu0, mu1, mu2, mu3);
    reinterpret_cast<float4*>(w_i2s)[fo] = make_float4(0.5f / sg0, 0.5f / sg1, 0.5f / sg2, 0.5f / sg3);
    reinterpret_cast<float4*>(w_m1v)[fo] = make_float4(pv0, pv1, pv2, pv3);
    reinterpret_cast<float4*>(w_m1q)[fo] = make_float4(pq0, pq1, pq2, pq3);

    const int o = c >> 2;
    const float bu = beta_u[o];
    float lt = logf(TWO_PIf * sg0 + EPSf) + logf(TWO_PIf * sg1 + EPSf)
             + logf(TWO_PIf * sg2 + EPSf) + logf(TWO_PIf * sg3 + EPSf);
    float ch = (4.f * bu - 0.5f * (logf(sg0 + EPSf) + logf(sg1 + EPSf)
                                 + logf(sg2 + EPSf) + logf(sg3 + EPSf))) * sumR1;
    ch += __shfl_xor(ch, 1); ch += __shfl_xor(ch, 2);
    lt += __shfl_xor(lt, 1); lt += __shfl_xor(lt, 2);
    if ((t & 3) == 0) {
      // inv_temp (it=0) = 0.01*(1-0.95) = 0.0005
      const float aj = 1.f / (1.f + expf(-(0.0005f * (beta_a[o] - ch))));
      w_base[site * NOc + o] = logf(aj + EPSf) - lt;
    }
    if (t == 0) w_sR1[site] = sumR1;
  }
}

// ---------------- K3: E-step + M-step-2 partials (register-direct, low-VGPR) ----
// grid 4608; block 256, min 4 waves/SIMD. site reversed for L2/L3 reuse of K1.
// Thread (kk = t>>5, o = t&31) owns votes[site,kk,i,o,0:16] (contiguous 64B).
// t<32 additionally owns the kk=8 tail row. Vote rows are consumed at load and
// reloaded (L1-hot, CSE-blocked) for accumulation -> minimal live set across
// the LSE shuffle chain.
__global__ __launch_bounds__(256, 4)
void em_k3(const float* __restrict__ votes, const float* __restrict__ acts_in,
           const float* __restrict__ w_mu1, const float* __restrict__ w_i2s,
           const float* __restrict__ w_base, float* __restrict__ w_part)
{
  const int site = (NSITE - 1) - (blockIdx.x >> 3);
  const int ig   = blockIdx.x & 7;
  const int t    = threadIdx.x;
  const int o    = t & 31;
  const int kk   = t >> 5;          // 0..7

  __shared__ float s_act[KIc];
  __shared__ float s_lse[2][16];    // [parity][wave*2 + {max, sumexp}] (8 used)
  __shared__ float s_p[33 * 128];   // 16896B block-reduction buffer

  s_act[t] = acts_in[site * KIc + t];
  if (t < 32) s_act[256 + t] = acts_in[site * KIc + 256 + t];
  // (visibility of s_act is covered by the first in-loop barrier)

  // per-thread mu/i2s tables for capsule o, straight from global (L2/L3-hot)
  float mu[16], is[16];
  {
    const float4* mp = reinterpret_cast<const float4*>(w_mu1 + (size_t)site * NPc) + o * 4;
    const float4* ip = reinterpret_cast<const float4*>(w_i2s + (size_t)site * NPc) + o * 4;
#pragma unroll
    for (int j = 0; j < 4; ++j) {
      const float4 a = mp[j];
      mu[4 * j] = a.x; mu[4 * j + 1] = a.y; mu[4 * j + 2] = a.z; mu[4 * j + 3] = a.w;
      const float4 b = ip[j];
      is[4 * j] = b.x; is[4 * j + 1] = b.y; is[4 * j + 2] = b.z; is[4 * j + 3] = b.w;
    }
  }
  const float lbase = w_base[site * NOc + o];

  float accv[16], accq[16], accw = 0.f;
#pragma unroll
  for (int a = 0; a < 16; ++a) { accv[a] = 0.f; accq[a] = 0.f; }

  const float4* vrow = reinterpret_cast<const float4*>(votes)
                     + (size_t)site * (KIc * 128) + o * 4;

  for (int ii = 0; ii < 4; ++ii) {
    const int i = ig * 4 + ii;
    const float4* p1 = vrow + (size_t)(kk * NIc + i) * 128;
    const float4* p2 = vrow + (size_t)(8 * NIc + i) * 128;

    // own row: consume into lp1 at load time (values NOT kept live)
    float lp1;
    {
      const float4 x0 = p1[0], x1 = p1[1], x2 = p1[2], x3 = p1[3];
      float d; lp1 = 0.f;
      d = x0.x - mu[0];  lp1 = fmaf(d * d, is[0],  lp1);
      d = x0.y - mu[1];  lp1 = fmaf(d * d, is[1],  lp1);
      d = x0.z - mu[2];  lp1 = fmaf(d * d, is[2],  lp1);
      d = x0.w - mu[3];  lp1 = fmaf(d * d, is[3],  lp1);
      d = x1.x - mu[4];  lp1 = fmaf(d * d, is[4],  lp1);
      d = x1.y - mu[5];  lp1 = fmaf(d * d, is[5],  lp1);
      d = x1.z - mu[6];  lp1 = fmaf(d * d, is[6],  lp1);
      d = x1.w - mu[7];  lp1 = fmaf(d * d, is[7],  lp1);
      d = x2.x - mu[8];  lp1 = fmaf(d * d, is[8],  lp1);
      d = x2.y - mu[9];  lp1 = fmaf(d * d, is[9],  lp1);
      d = x2.z - mu[10]; lp1 = fmaf(d * d, is[10], lp1);
      d = x2.w - mu[11]; lp1 = fmaf(d * d, is[11], lp1);
      d = x3.x - mu[12]; lp1 = fmaf(d * d, is[12], lp1);
      d = x3.y - mu[13]; lp1 = fmaf(d * d, is[13], lp1);
      d = x3.z - mu[14]; lp1 = fmaf(d * d, is[14], lp1);
      d = x3.w - mu[15]; lp1 = fmaf(d * d, is[15], lp1);
    }
    const float ln1 = lbase - lp1;

    // kk=8 tail (lanes 0-31): compute ln2, values not kept live
    float ln2 = -1e30f;
    if (t < 32) {
      float lp2 = 0.f;
#pragma unroll
      for (int j = 0; j < 4; ++j) {
        const float4 x = p2[j];
        float d;
        d = x.x - mu[4 * j];     lp2 = fmaf(d * d, is[4 * j],     lp2);
        d = x.y - mu[4 * j + 1]; lp2 = fmaf(d * d, is[4 * j + 1], lp2);
        d = x.z - mu[4 * j + 2]; lp2 = fmaf(d * d, is[4 * j + 2], lp2);
        d = x.w - mu[4 * j + 3]; lp2 = fmaf(d * d, is[4 * j + 3], lp2);
      }
      ln2 = lbase - lp2;
    }

    // per-wave LSE partials -> single barrier -> register combine.
    const float mw = wave_max_all(fmaxf(ln1, ln2));
    float e = expf(ln1 - mw) + ((t < 32) ? expf(ln2 - mw) : 0.f);
    e = wave_sum(e);                       // lane 0 holds the wave total
    if ((t & 63) == 0) {
      s_lse[ii & 1][(t >> 6) * 2 + 0] = mw;
      s_lse[ii & 1][(t >> 6) * 2 + 1] = e;
    }
    __syncthreads();
    const float m0 = s_lse[ii & 1][0], e0 = s_lse[ii & 1][1];
    const float m1 = s_lse[ii & 1][2], e1 = s_lse[ii & 1][3];
    const float m2 = s_lse[ii & 1][4], e2 = s_lse[ii & 1][5];
    const float m3 = s_lse[ii & 1][6], e3 = s_lse[ii & 1][7];
    const float gm = fmaxf(fmaxf(m0, m1), fmaxf(m2, m3));
    const float den = e0 * expf(m0 - gm) + e1 * expf(m1 - gm)
                    + e2 * expf(m2 - gm) + e3 * expf(m3 - gm);
    const float logden = gm + logf(den);

    // weights + moment accumulation; rows reloaded L1-hot, CSE blocked
    const float w1 = expf(ln1 - logden) * s_act[kk * NIc + i] * 0.8f;
    accw += w1;
    {
      uintptr_t up = (uintptr_t)p1;
      asm volatile("" : "+v"(up));       // opaque: forces true reload (frees regs above)
      const float4* pr = (const float4*)up;
#pragma unroll
      for (int j = 0; j < 4; ++j) {
        const float4 x = pr[j];
        accv[4 * j]     = fmaf(w1, x.x, accv[4 * j]);
        accq[4 * j]     = fmaf(w1, x.x * x.x, accq[4 * j]);
        accv[4 * j + 1] = fmaf(w1, x.y, accv[4 * j + 1]);
        accq[4 * j + 1] = fmaf(w1, x.y * x.y, accq[4 * j + 1]);
        accv[4 * j + 2] = fmaf(w1, x.z, accv[4 * j + 2]);
        accq[4 * j + 2] = fmaf(w1, x.z * x.z, accq[4 * j + 2]);
        accv[4 * j + 3] = fmaf(w1, x.w, accv[4 * j + 3]);
        accq[4 * j + 3] = fmaf(w1, x.w * x.w, accq[4 * j + 3]);
      }
    }
    if (t < 32) {
      const float w2 = expf(ln2 - logden) * s_act[8 * NIc + i] * 0.8f;
      accw += w2;
      uintptr_t up = (uintptr_t)p2;
      asm volatile("" : "+v"(up));
      const float4* pr = (const float4*)up;
#pragma unroll
      for (int j = 0; j < 4; ++j) {
        const float4 x = pr[j];
        accv[4 * j]     = fmaf(w2, x.x, accv[4 * j]);
        accq[4 * j]     = fmaf(w2, x.x * x.x, accq[4 * j]);
        accv[4 * j + 1] = fmaf(w2, x.y, accv[4 * j + 1]);
        accq[4 * j + 1] = fmaf(w2, x.y * x.y, accq[4 * j + 1]);
        accv[4 * j + 2] = fmaf(w2, x.z, accv[4 * j + 2]);
        accq[4 * j + 2] = fmaf(w2, x.z * x.z, accq[4 * j + 2]);
        accv[4 * j + 3] = fmaf(w2, x.w, accv[4 * j + 3]);
        accq[4 * j + 3] = fmaf(w2, x.w * x.w, accq[4 * j + 3]);
      }
    }
  }

  // ---- block reduction over kk: shfl fold + 4-wave LDS combine ----
  accw += __shfl_xor(accw, 32);
#pragma unroll
  for (int a = 0; a < 16; ++a) {
    accv[a] += __shfl_xor(accv[a], 32);
    accq[a] += __shfl_xor(accq[a], 32);
  }
  {
    const int l = t & 63, wv = t >> 6;
    if (l < 32) {
#pragma unroll
      for (int a = 0; a < 16; ++a) {
        s_p[a * 128 + wv * 32 + l] = accv[a];
        s_p[(16 + a) * 128 + wv * 32 + l] = accq[a];
      }
      s_p[32 * 128 + wv * 32 + l] = accw;
    }
  }
  __syncthreads();
  float* wp = w_part + (size_t)(site * 8 + ig) * (33 * 32);
  for (int j = t >> 5; j < 33; j += 8) {
    const float s = s_p[j * 128 + o] + s_p[j * 128 + 32 + o]
                  + s_p[j * 128 + 64 + o] + s_p[j * 128 + 96 + o];
    wp[j * 32 + o] = s;
  }
}

// ---------------- K4: finalize ----------------
__global__ __launch_bounds__(256)
void em_k4(const float* __restrict__ beta_a, const float* __restrict__ beta_u,
           const float* __restrict__ w_m1v, const float* __restrict__ w_m1q,
           const float* __restrict__ w_sR1, const float* __restrict__ w_part,
           float* __restrict__ out)
{
  const int site = blockIdx.x;
  const int t    = threadIdx.x;
  const int oB   = t & 31;
  const int a2B  = (t >> 5) * 2;

  __shared__ float s_M[33 * 32];
  __shared__ float s_c[256];

  for (int j = t >> 5; j < 33; j += 8) {
    float s = 0.f;
#pragma unroll
    for (int g = 0; g < 8; ++g)
      s += w_part[(size_t)(site * 8 + g) * (33 * 32) + j * 32 + oB];
    s_M[j * 32 + oB] = s;
  }
  __syncthreads();

  const float sumR1 = w_sR1[site];
  const float sumR  = s_M[32 * 32 + oB] + 0.2f * sumR1;
  const float sRe   = sumR + EPSf;
  const float sRx   = sumR + 2.f * EPSf;
  const int p = oB * NAc + a2B;

  const float Mva = s_M[a2B * 32 + oB]        + 0.2f * w_m1v[(size_t)site * NPc + p];
  const float Mvb = s_M[(a2B + 1) * 32 + oB]  + 0.2f * w_m1v[(size_t)site * NPc + p + 1];
  const float Mqa = s_M[(16 + a2B) * 32 + oB] + 0.2f * w_m1q[(size_t)site * NPc + p];
  const float Mqb = s_M[(17 + a2B) * 32 + oB] + 0.2f * w_m1q[(size_t)site * NPc + p + 1];

  const float mua = Mva / sRe;
  const float mub = Mvb / sRe;
  const float sga = fmaxf((Mqa - mua * mua * sRx) / sRe, 0.f);
  const float sgb = fmaxf((Mqb - mub * mub * sRx) / sRe, 0.f);

  reinterpret_cast<float2*>(out + (size_t)site * NPc)[p >> 1] = make_float2(mua, mub);

  const float bu = beta_u[oB];
  s_c[t] = (bu - 0.5f * logf(sga + EPSf)) * sumR
         + (bu - 0.5f * logf(sgb + EPSf)) * sumR;
  __syncthreads();
  if (t < NOc) {
    float c = 0.f;
#pragma unroll
    for (int k = 0; k < 8; ++k) c += s_c[t + 32 * k];
    // inv_temp (it_idx=ITERATIONS=2) = 0.01*(1-0.95^3) = 0.00142625
    const float aj = 1.f / (1.f + expf(-(0.00142625f * (beta_a[t] - c))));
    out[(size_t)NSITE * NPc + site * NOc + t] = aj;
  }
}

extern "C" void kernel_launch(void* const* d_in, const int* in_sizes, int n_in,
                              void* d_out, int out_size, void* d_ws, size_t ws_size,
                              hipStream_t stream) {
  const float* votes  = (const float*)d_in[0];
  const float* acts   = (const float*)d_in[1];
  const float* beta_a = (const float*)d_in[2];
  const float* beta_u = (const float*)d_in[3];
  float* out = (float*)d_out;

  float* ws = (float*)d_ws;
  const size_t SP = (size_t)NSITE * NPc;        // 294912
  float* w_mu1  = ws;
  float* w_i2s  = ws + SP;
  float* w_m1v  = ws + 2 * SP;
  float* w_m1q  = ws + 3 * SP;
  float* w_base = ws + 4 * SP;                  // 576*32
  float* w_sR1  = w_base + NSITE * NOc;         // 576 (padded to 1024)
  float* w_part = w_sR1 + 1024;                 // 4608*33*32 floats (~19.5MB)

  em_k1<<<NSITE * 4, 128, 0, stream>>>(votes, acts, beta_a, beta_u,
                                       w_mu1, w_i2s, w_m1v, w_m1q, w_base, w_sR1);
  em_k3<<<NSITE * 8, 256, 0, stream>>>(votes, acts, w_mu1, w_i2s, w_base, w_part);
  em_k4<<<NSITE, 256, 0, stream>>>(beta_a, beta_u, w_m1v, w_m1q, w_sR1, w_part, out);
}